// Round 32
// baseline (211.167 us; speedup 1.0000x reference)
//
#include <hip/hip_runtime.h>
#include <hip/hip_bf16.h>

#define N_LATENT 64
#define N_OUT    64
#define CAP      256   // rows/sample capacity: mean 65.5, sd ~8 -> 23 sigma
#define CSTRIDE  16    // cursor padded to 64 B/sample (round-21: -10.5 us)
#define NWAVES   5     // 1:1 wave:tile for the typical 5-tile sample (r23)
#define TPAD     68    // LDS tile row pitch: 16B-aligned, bank-spread (r26)
#define NTHR     (64 * NWAVES)

typedef __attribute__((ext_vector_type(8))) _Float16 f16x8;
typedef __attribute__((ext_vector_type(4))) float    f32x4;

union U4H8 { uint4 u4; f16x8 h8; };

// Fused build+barrier+compute (r27 structure, which was CORRECT at absmax
// 0.25 but 209us). Root cause of r27's slowness: the spin polled with
// atomicAdd(bar,0) -- an atomic RMW -- so 1000 pollers serialized exclusive
// ownership of one cacheline. THE ONLY CHANGE HERE: poll with a relaxed
// atomic LOAD (read-shared, no ownership bounce) + s_sleep(32) backoff
// (~0.85us poll interval). Fencing, staging-under-build overlap, and the
// compute path are byte-identical to r27/r26.
// Co-residency arithmetic: LDS 30KB -> 5 blocks/CU -> capacity 1280 >= 1000
// blocks -> barrier cannot deadlock. bar+cursors zeroed by the one memset.
__global__ __launch_bounds__(NTHR, 5) void fused_decoder_kernel(
    const float* __restrict__ u,
    const int*   __restrict__ sid,
    const float* __restrict__ amat,
    const float* __restrict__ offsets,
    int*         __restrict__ bar,
    int*         __restrict__ cursor,
    int*         __restrict__ list,
    float*       __restrict__ out,
    int batch, int n_sample)
{
    __shared__ uint  Bf[8 * 64 * 4];           // B fragments: 8 KB
    __shared__ float Ot[NWAVES][16 * TPAD];    // per-wave acc tiles: 21.76 KB

    const int s    = blockIdx.x;               // sample id, grid == n_sample
    const int tid  = threadIdx.x;
    const int lane = tid & 63;
    const int wave = tid >> 6;                 // 0..4

    const float* __restrict__ Ag  = amat + (size_t)s * (N_LATENT * N_OUT);
    const int*   __restrict__ lst = list + s * CAP;

    // ---- (a) stage B fragments (overlaps the build's memory latency) ----
    for (int c = wave; c < 8; c += NWAVES) {
        const int kk  = c >> 2;
        const int nt  = c & 3;
        const int kb  = kk * 32 + (lane >> 4) * 8;   // 8 contiguous k
        const int col = nt * 16 + (lane & 15);
        U4H8 x;
#pragma unroll
        for (int j = 0; j < 8; ++j)
            x.h8[j] = (_Float16)Ag[(kb + j) * N_OUT + col];
        *((uint4*)&Bf[(c * 64 + lane) * 4]) = x.u4;
    }

    // ---- (b) build contribution: this block's contiguous row range ----
    {
        const int rows_per = (batch + n_sample - 1) / n_sample;   // 66
        const int r0 = s * rows_per;
        int r1 = r0 + rows_per; if (r1 > batch) r1 = batch;
        for (int i = r0 + tid; i < r1; i += NTHR) {
            const int si = sid[i];
            const int p  = atomicAdd(&cursor[si * CSTRIDE], 1);
            if (p < CAP) list[si * CAP + p] = i;
        }
    }

    // ---- (c) device barrier: release -> count -> LOAD-spin -> acquire ----
    __threadfence();                           // release: list writes visible
    __syncthreads();
    if (tid == 0) {
        atomicAdd(bar, 1);
        while (__hip_atomic_load(bar, __ATOMIC_RELAXED,
                                 __HIP_MEMORY_SCOPE_AGENT) < n_sample)
            __builtin_amdgcn_s_sleep(32);      // ~0.85us; read-only poll
        __threadfence();                       // acquire: invalidate L1
    }
    __syncthreads();

    // ---- (d) compute (round-26 proven path) ----
    int n = cursor[s * CSTRIDE];
    n = (n < CAP) ? n : CAP;
    if (n == 0) return;

    const int tiles = (n + 15) >> 4;

    const float4 offv = *(const float4*)(offsets + (size_t)s * N_OUT + (lane & 15) * 4);
    float* __restrict__ myT = &Ot[wave][0];

    for (int t = wave; t < tiles; t += NWAVES) {
        // A fragment: 16 rows (lane&15), k-chunk (lane>>4)*8
        const int ridx = t * 16 + (lane & 15);
        const int brow = lst[(ridx < n) ? ridx : 0];      // pad: row list[0]
        const float* __restrict__ up =
            u + (size_t)brow * N_LATENT + ((lane >> 4) * 8);
        f16x8 a0, a1;
        {
            const float4 p0 = *(const float4*)(up);
            const float4 p1 = *(const float4*)(up + 4);
            const float4 p2 = *(const float4*)(up + 32);  // kk=1: k += 32
            const float4 p3 = *(const float4*)(up + 36);
            a0[0] = (_Float16)p0.x; a0[1] = (_Float16)p0.y;
            a0[2] = (_Float16)p0.z; a0[3] = (_Float16)p0.w;
            a0[4] = (_Float16)p1.x; a0[5] = (_Float16)p1.y;
            a0[6] = (_Float16)p1.z; a0[7] = (_Float16)p1.w;
            a1[0] = (_Float16)p2.x; a1[1] = (_Float16)p2.y;
            a1[2] = (_Float16)p2.z; a1[3] = (_Float16)p2.w;
            a1[4] = (_Float16)p3.x; a1[5] = (_Float16)p3.y;
            a1[6] = (_Float16)p3.z; a1[7] = (_Float16)p3.w;
        }

        // MFMA per n-tile; dump acc to the wave's LDS tile
#pragma unroll
        for (int nt = 0; nt < 4; ++nt) {
            U4H8 b0, b1;
            b0.u4 = *((const uint4*)&Bf[((0 * 4 + nt) * 64 + lane) * 4]);
            b1.u4 = *((const uint4*)&Bf[((1 * 4 + nt) * 64 + lane) * 4]);
            f32x4 acc = {0.f, 0.f, 0.f, 0.f};
            acc = __builtin_amdgcn_mfma_f32_16x16x32_f16(a0, b0.h8, acc, 0, 0, 0);
            acc = __builtin_amdgcn_mfma_f32_16x16x32_f16(a1, b1.h8, acc, 0, 0, 0);

            const int col = nt * 16 + (lane & 15);
#pragma unroll
            for (int r = 0; r < 4; ++r)
                myT[((lane >> 4) * 4 + r) * TPAD + col] = acc[r];
        }
        asm volatile("s_waitcnt lgkmcnt(0)" ::: "memory");

        // coalesced epilogue: 4 passes x {float4 u-read, add, float4 store}
#pragma unroll
        for (int p = 0; p < 4; ++p) {
            const int r2    = p * 4 + (lane >> 4);
            const int ridx2 = t * 16 + r2;
            if (ridx2 < n) {
                const int brow2 = lst[ridx2];
                const float* __restrict__ urow =
                    u + (size_t)brow2 * N_LATENT + (lane & 15) * 4;
                float* __restrict__ orow =
                    out + (size_t)brow2 * N_OUT + (lane & 15) * 4;
                const float4 uq = *(const float4*)urow;
                const float4 tv = *(const float4*)(myT + r2 * TPAD + (lane & 15) * 4);
                float4 o;
                o.x = uq.x + tv.x + offv.x;
                o.y = uq.y + tv.y + offv.y;
                o.z = uq.z + tv.z + offv.z;
                o.w = uq.w + tv.w + offv.w;
                *(float4*)orow = o;
            }
        }
    }
}

extern "C" void kernel_launch(void* const* d_in, const int* in_sizes, int n_in,
                              void* d_out, int out_size, void* d_ws, size_t ws_size,
                              hipStream_t stream)
{
    const float* u       = (const float*)d_in[0];
    const int*   sid     = (const int*)d_in[1];
    const float* amat    = (const float*)d_in[2];
    const float* offsets = (const float*)d_in[3];
    float*       out     = (float*)d_out;

    int batch    = in_sizes[0] / N_LATENT;            // 65536
    int n_sample = in_sizes[2] / (N_LATENT * N_OUT);  // 1000

    // ws layout (ints): [0,16) bar(+pad) | [16, 16+n_sample*CSTRIDE) cursors
    //                   | then n_sample*CAP lists
    int* bar    = (int*)d_ws;
    int* cursor = bar + 16;
    int* list   = cursor + (size_t)n_sample * CSTRIDE;

    // one memset zeroes bar + cursors (contiguous)
    hipMemsetAsync(bar, 0, (16 + (size_t)n_sample * CSTRIDE) * sizeof(int), stream);

    fused_decoder_kernel<<<n_sample, NTHR, 0, stream>>>(
        u, sid, amat, offsets, bar, cursor, list, out, batch, n_sample);
}

// Round 33
// 163.371 us; speedup vs baseline: 1.2926x; 1.2926x over previous
//
#include <hip/hip_runtime.h>
#include <hip/hip_bf16.h>

#define N_LATENT 64
#define N_OUT    64
#define CAP      256   // rows/sample capacity: mean 65.5, sd ~8 -> 23 sigma
#define CSTRIDE  16    // cursor padded to 64 B/sample (round-21: -10.5 us)
#define NWAVES   5     // 1:1 wave:tile for the typical 5-tile sample (r23)
#define TPAD     68    // LDS tile row pitch: 16B-aligned, bank-spread (r26)
#define NTHR     (64 * NWAVES)

typedef __attribute__((ext_vector_type(8))) _Float16 f16x8;
typedef __attribute__((ext_vector_type(4))) float    f32x4;

union U4H8 { uint4 u4; f16x8 h8; };

// Fused build+barrier+compute, 3rd barrier design.
// r27 (RMW-spin) = 209us, r32 (load-spin) = 211us -> poll type irrelevant;
// the cost is 1000 arrival atomicAdds on ONE line: each device-scope RMW
// migrates exclusive line ownership across 8 XCDs (~200ns serialized).
// FIX: hierarchical arrival. (1) blocks add to their OWN XCD's counter
// (s_getreg HW_REG_XCC_ID, 8 padded lines -> no cross-XCD migration);
// (2) only block 0 polls the 8-counter sum; (3) block 0 writes a go flag,
// everyone else load-polls go (read-only broadcast). Fence chain identical
// in strength to the functionally-correct r27/r32. Compute path byte-
// identical to the r26 champion -> absmax 0.25.
// Co-residency: LDS 30KB -> 5 blocks/CU -> 1280 >= 1000, no deadlock
// (r27/r32 completing proves residency).
__global__ __launch_bounds__(NTHR, 5) void fused_decoder_kernel(
    const float* __restrict__ u,
    const int*   __restrict__ sid,
    const float* __restrict__ amat,
    const float* __restrict__ offsets,
    int*         __restrict__ barr,     // [0]=go, [16+x*16]=XCD-x arrivals
    int*         __restrict__ cursor,
    int*         __restrict__ list,
    float*       __restrict__ out,
    int batch, int n_sample)
{
    __shared__ uint  Bf[8 * 64 * 4];           // B fragments: 8 KB
    __shared__ float Ot[NWAVES][16 * TPAD];    // per-wave acc tiles: 21.76 KB

    const int s    = blockIdx.x;               // sample id, grid == n_sample
    const int tid  = threadIdx.x;
    const int lane = tid & 63;
    const int wave = tid >> 6;                 // 0..4

    const float* __restrict__ Ag  = amat + (size_t)s * (N_LATENT * N_OUT);
    const int*   __restrict__ lst = list + s * CAP;

    // ---- (a) stage B fragments (overlaps the build's memory latency) ----
    for (int c = wave; c < 8; c += NWAVES) {
        const int kk  = c >> 2;
        const int nt  = c & 3;
        const int kb  = kk * 32 + (lane >> 4) * 8;   // 8 contiguous k
        const int col = nt * 16 + (lane & 15);
        U4H8 x;
#pragma unroll
        for (int j = 0; j < 8; ++j)
            x.h8[j] = (_Float16)Ag[(kb + j) * N_OUT + col];
        *((uint4*)&Bf[(c * 64 + lane) * 4]) = x.u4;
    }

    // ---- (b) build contribution: this block's contiguous row range ----
    {
        const int rows_per = (batch + n_sample - 1) / n_sample;   // 66
        const int r0 = s * rows_per;
        int r1 = r0 + rows_per; if (r1 > batch) r1 = batch;
        for (int i = r0 + tid; i < r1; i += NTHR) {
            const int si = sid[i];
            const int p  = atomicAdd(&cursor[si * CSTRIDE], 1);
            if (p < CAP) list[si * CAP + p] = i;
        }
    }

    // ---- (c) hierarchical device barrier ----
    __threadfence();                           // release: list writes visible
    __syncthreads();
    if (tid == 0) {
        uint xcc;
        asm volatile("s_getreg_b32 %0, hwreg(HW_REG_XCC_ID)" : "=s"(xcc));
        atomicAdd(&barr[16 + (xcc & 7) * 16], 1);    // XCD-local arrival line
        if (s == 0) {
            int sum = 0;
            while (sum < n_sample) {
                __builtin_amdgcn_s_sleep(16);        // ~0.43us
                sum = 0;
#pragma unroll
                for (int x = 0; x < 8; ++x)
                    sum += __hip_atomic_load(&barr[16 + x * 16],
                                             __ATOMIC_RELAXED,
                                             __HIP_MEMORY_SCOPE_AGENT);
            }
            __hip_atomic_store(&barr[0], 1, __ATOMIC_RELEASE,
                               __HIP_MEMORY_SCOPE_AGENT);
        } else {
            while (__hip_atomic_load(&barr[0], __ATOMIC_RELAXED,
                                     __HIP_MEMORY_SCOPE_AGENT) == 0)
                __builtin_amdgcn_s_sleep(64);        // ~1.7us; read-only poll
        }
        __threadfence();                       // acquire
    }
    __syncthreads();

    // ---- (d) compute (round-26 proven path) ----
    int n = cursor[s * CSTRIDE];
    n = (n < CAP) ? n : CAP;
    if (n == 0) return;

    const int tiles = (n + 15) >> 4;

    const float4 offv = *(const float4*)(offsets + (size_t)s * N_OUT + (lane & 15) * 4);
    float* __restrict__ myT = &Ot[wave][0];

    for (int t = wave; t < tiles; t += NWAVES) {
        // A fragment: 16 rows (lane&15), k-chunk (lane>>4)*8
        const int ridx = t * 16 + (lane & 15);
        const int brow = lst[(ridx < n) ? ridx : 0];      // pad: row list[0]
        const float* __restrict__ up =
            u + (size_t)brow * N_LATENT + ((lane >> 4) * 8);
        f16x8 a0, a1;
        {
            const float4 p0 = *(const float4*)(up);
            const float4 p1 = *(const float4*)(up + 4);
            const float4 p2 = *(const float4*)(up + 32);  // kk=1: k += 32
            const float4 p3 = *(const float4*)(up + 36);
            a0[0] = (_Float16)p0.x; a0[1] = (_Float16)p0.y;
            a0[2] = (_Float16)p0.z; a0[3] = (_Float16)p0.w;
            a0[4] = (_Float16)p1.x; a0[5] = (_Float16)p1.y;
            a0[6] = (_Float16)p1.z; a0[7] = (_Float16)p1.w;
            a1[0] = (_Float16)p2.x; a1[1] = (_Float16)p2.y;
            a1[2] = (_Float16)p2.z; a1[3] = (_Float16)p2.w;
            a1[4] = (_Float16)p3.x; a1[5] = (_Float16)p3.y;
            a1[6] = (_Float16)p3.z; a1[7] = (_Float16)p3.w;
        }

        // MFMA per n-tile; dump acc to the wave's LDS tile
#pragma unroll
        for (int nt = 0; nt < 4; ++nt) {
            U4H8 b0, b1;
            b0.u4 = *((const uint4*)&Bf[((0 * 4 + nt) * 64 + lane) * 4]);
            b1.u4 = *((const uint4*)&Bf[((1 * 4 + nt) * 64 + lane) * 4]);
            f32x4 acc = {0.f, 0.f, 0.f, 0.f};
            acc = __builtin_amdgcn_mfma_f32_16x16x32_f16(a0, b0.h8, acc, 0, 0, 0);
            acc = __builtin_amdgcn_mfma_f32_16x16x32_f16(a1, b1.h8, acc, 0, 0, 0);

            const int col = nt * 16 + (lane & 15);
#pragma unroll
            for (int r = 0; r < 4; ++r)
                myT[((lane >> 4) * 4 + r) * TPAD + col] = acc[r];
        }
        asm volatile("s_waitcnt lgkmcnt(0)" ::: "memory");

        // coalesced epilogue: 4 passes x {float4 u-read, add, float4 store}
#pragma unroll
        for (int p = 0; p < 4; ++p) {
            const int r2    = p * 4 + (lane >> 4);
            const int ridx2 = t * 16 + r2;
            if (ridx2 < n) {
                const int brow2 = lst[ridx2];
                const float* __restrict__ urow =
                    u + (size_t)brow2 * N_LATENT + (lane & 15) * 4;
                float* __restrict__ orow =
                    out + (size_t)brow2 * N_OUT + (lane & 15) * 4;
                const float4 uq = *(const float4*)urow;
                const float4 tv = *(const float4*)(myT + r2 * TPAD + (lane & 15) * 4);
                float4 o;
                o.x = uq.x + tv.x + offv.x;
                o.y = uq.y + tv.y + offv.y;
                o.z = uq.z + tv.z + offv.z;
                o.w = uq.w + tv.w + offv.w;
                *(float4*)orow = o;
            }
        }
    }
}

extern "C" void kernel_launch(void* const* d_in, const int* in_sizes, int n_in,
                              void* d_out, int out_size, void* d_ws, size_t ws_size,
                              hipStream_t stream)
{
    const float* u       = (const float*)d_in[0];
    const int*   sid     = (const int*)d_in[1];
    const float* amat    = (const float*)d_in[2];
    const float* offsets = (const float*)d_in[3];
    float*       out     = (float*)d_out;

    int batch    = in_sizes[0] / N_LATENT;            // 65536
    int n_sample = in_sizes[2] / (N_LATENT * N_OUT);  // 1000

    // ws layout (ints): [0,256) barrier region (go + 8 padded XCD counters)
    //                   | [256, 256+n_sample*CSTRIDE) cursors | then lists
    int* barr   = (int*)d_ws;
    int* cursor = barr + 256;
    int* list   = cursor + (size_t)n_sample * CSTRIDE;

    // one memset zeroes barrier region + cursors (contiguous)
    hipMemsetAsync(barr, 0, (256 + (size_t)n_sample * CSTRIDE) * sizeof(int), stream);

    fused_decoder_kernel<<<n_sample, NTHR, 0, stream>>>(
        u, sid, amat, offsets, barr, cursor, list, out, batch, n_sample);
}

// Round 34
// 25.698 us; speedup vs baseline: 8.2174x; 6.3574x over previous
//
#include <hip/hip_runtime.h>
#include <hip/hip_bf16.h>

#define N_LATENT 64
#define N_OUT    64
#define CAP      256   // rows/sample capacity: mean 65.5, sd ~8 -> 23 sigma
#define CSTRIDE  16    // cursor padded to 64 B/sample (round-21: -10.5 us)
#define NWAVES   5     // 1:1 wave:tile for the typical 5-tile sample (r23)
#define TPAD     68    // LDS tile row pitch (floats): 16B-aligned, bank-spread

typedef __attribute__((ext_vector_type(8))) _Float16 f16x8;
typedef __attribute__((ext_vector_type(4))) float    f32x4;

union U4H8 { uint4 u4; f16x8 h8; };

// CHAMPION (r26: 25.4us, r29 repro: 26.2us). 3-node pipeline:
// memset(64KB cursors) -> build (1 pass, padded-cursor atomics) -> compute.
// Fusion alternatives all measured and falsified: cooperative launch
// no-ops under graph capture (r18); grid barriers cost ~150-210us for
// 1000 blocks regardless of design (r27 RMW-spin 209, r32 load-spin 211,
// r33 hierarchical XCD-local 163) -- device-scope atomic visibility across
// 8 non-coherent XCDs is the platform constant. Single-kernel redundant
// scan = 33.3us (r28). This 3-node structure is the measured optimum.
__global__ __launch_bounds__(256) void build_lists_kernel(
    const int* __restrict__ sid,
    int* __restrict__ cursor,
    int* __restrict__ list,
    int batch)
{
    const int i = blockIdx.x * blockDim.x + threadIdx.x;
    if (i < batch) {
        const int s = sid[i];
        const int p = atomicAdd(&cursor[s * CSTRIDE], 1);
        if (p < CAP) list[s * CAP + p] = i;
    }
}

// One block (320 thr = 5 waves) per sample. B-frags of A[s] (f16) staged
// once to LDS; wave w owns tile w (1:1 for the typical 5-tile sample).
// Per 16-row tile: 8x mfma_f32_16x16x32_f16 (4 n-tiles x 2 k-halves).
// Epilogue: acc -> per-wave LDS [16][TPAD] -> 4 coalesced float4 passes
// {u-read, add, store} (r26: -3.9us vs scattered scalar epilogue).
// k-map identical for A/B fragments (self-consistent bijection); C/D map
// col=lane&15, row=(lane>>4)*4+r. Math order (u+acc)+off -> absmax 0.25.
__global__ __launch_bounds__(64 * NWAVES) void decoder_mfma_kernel(
    const float* __restrict__ u,
    const float* __restrict__ amat,
    const float* __restrict__ offsets,
    const int*   __restrict__ cursor,
    const int*   __restrict__ list,
    float*       __restrict__ out)
{
    __shared__ uint  Bf[8 * 64 * 4];           // B fragments: 8 KB
    __shared__ float Ot[NWAVES][16 * TPAD];    // per-wave acc tiles: 21.25 KB

    const int s    = blockIdx.x;
    const int tid  = threadIdx.x;
    const int lane = tid & 63;
    const int wave = tid >> 6;                 // 0..4

    int n = cursor[s * CSTRIDE];
    n = (n < CAP) ? n : CAP;
    if (n == 0) return;                        // uniform exit, before barrier

    const float* __restrict__ Ag  = amat + (size_t)s * (N_LATENT * N_OUT);
    const int*   __restrict__ lst = list + s * CAP;

    // stage B fragments: combo c = kk*4+nt over 5 waves
    for (int c = wave; c < 8; c += NWAVES) {
        const int kk  = c >> 2;
        const int nt  = c & 3;
        const int kb  = kk * 32 + (lane >> 4) * 8;   // 8 contiguous k
        const int col = nt * 16 + (lane & 15);
        U4H8 x;
#pragma unroll
        for (int j = 0; j < 8; ++j)
            x.h8[j] = (_Float16)Ag[(kb + j) * N_OUT + col];
        *((uint4*)&Bf[(c * 64 + lane) * 4]) = x.u4;
    }
    __syncthreads();

    const int tiles = (n + 15) >> 4;

    // epilogue per-lane offsets: cols (lane&15)*4 .. +3
    const float4 offv = *(const float4*)(offsets + (size_t)s * N_OUT + (lane & 15) * 4);

    float* __restrict__ myT = &Ot[wave][0];

    for (int t = wave; t < tiles; t += NWAVES) {
        // A fragment: 16 rows (lane&15), k-chunk (lane>>4)*8
        const int ridx = t * 16 + (lane & 15);
        const int brow = lst[(ridx < n) ? ridx : 0];      // pad: row list[0]
        const float* __restrict__ up =
            u + (size_t)brow * N_LATENT + ((lane >> 4) * 8);
        f16x8 a0, a1;
        {
            const float4 p0 = *(const float4*)(up);
            const float4 p1 = *(const float4*)(up + 4);
            const float4 p2 = *(const float4*)(up + 32);  // kk=1: k += 32
            const float4 p3 = *(const float4*)(up + 36);
            a0[0] = (_Float16)p0.x; a0[1] = (_Float16)p0.y;
            a0[2] = (_Float16)p0.z; a0[3] = (_Float16)p0.w;
            a0[4] = (_Float16)p1.x; a0[5] = (_Float16)p1.y;
            a0[6] = (_Float16)p1.z; a0[7] = (_Float16)p1.w;
            a1[0] = (_Float16)p2.x; a1[1] = (_Float16)p2.y;
            a1[2] = (_Float16)p2.z; a1[3] = (_Float16)p2.w;
            a1[4] = (_Float16)p3.x; a1[5] = (_Float16)p3.y;
            a1[6] = (_Float16)p3.z; a1[7] = (_Float16)p3.w;
        }

        // MFMA per n-tile; dump acc to the wave's LDS tile
#pragma unroll
        for (int nt = 0; nt < 4; ++nt) {
            U4H8 b0, b1;
            b0.u4 = *((const uint4*)&Bf[((0 * 4 + nt) * 64 + lane) * 4]);
            b1.u4 = *((const uint4*)&Bf[((1 * 4 + nt) * 64 + lane) * 4]);
            f32x4 acc = {0.f, 0.f, 0.f, 0.f};
            acc = __builtin_amdgcn_mfma_f32_16x16x32_f16(a0, b0.h8, acc, 0, 0, 0);
            acc = __builtin_amdgcn_mfma_f32_16x16x32_f16(a1, b1.h8, acc, 0, 0, 0);

            const int col = nt * 16 + (lane & 15);
#pragma unroll
            for (int r = 0; r < 4; ++r)
                myT[((lane >> 4) * 4 + r) * TPAD + col] = acc[r];
        }
        // DS ops are in-order per wave; wait anyway before cross-lane read
        asm volatile("s_waitcnt lgkmcnt(0)" ::: "memory");

        // coalesced epilogue: 4 passes x {float4 u-read, add, float4 store}
#pragma unroll
        for (int p = 0; p < 4; ++p) {
            const int r2    = p * 4 + (lane >> 4);
            const int ridx2 = t * 16 + r2;
            if (ridx2 < n) {
                const int brow2 = lst[ridx2];
                const float* __restrict__ urow =
                    u + (size_t)brow2 * N_LATENT + (lane & 15) * 4;
                float* __restrict__ orow =
                    out + (size_t)brow2 * N_OUT + (lane & 15) * 4;
                const float4 uq = *(const float4*)urow;
                const float4 tv = *(const float4*)(myT + r2 * TPAD + (lane & 15) * 4);
                float4 o;
                o.x = uq.x + tv.x + offv.x;
                o.y = uq.y + tv.y + offv.y;
                o.z = uq.z + tv.z + offv.z;
                o.w = uq.w + tv.w + offv.w;
                *(float4*)orow = o;
            }
        }
    }
}

extern "C" void kernel_launch(void* const* d_in, const int* in_sizes, int n_in,
                              void* d_out, int out_size, void* d_ws, size_t ws_size,
                              hipStream_t stream)
{
    const float* u       = (const float*)d_in[0];
    const int*   sid     = (const int*)d_in[1];
    const float* amat    = (const float*)d_in[2];
    const float* offsets = (const float*)d_in[3];
    float*       out     = (float*)d_out;

    const int batch    = in_sizes[0] / N_LATENT;            // 65536
    const int n_sample = in_sizes[2] / (N_LATENT * N_OUT);  // 1000

    // ws layout (ints): [0, n_sample*CSTRIDE) padded cursors
    //                   | [n_sample*CSTRIDE, +n_sample*CAP) lists
    int* cursor = (int*)d_ws;
    int* list   = cursor + (size_t)n_sample * CSTRIDE;

    hipMemsetAsync(cursor, 0, (size_t)n_sample * CSTRIDE * sizeof(int), stream);

    build_lists_kernel<<<(batch + 255) / 256, 256, 0, stream>>>(
        sid, cursor, list, batch);

    decoder_mfma_kernel<<<n_sample, 64 * NWAVES, 0, stream>>>(
        u, amat, offsets, cursor, list, out);
}